// Round 6
// baseline (250.819 us; speedup 1.0000x reference)
//
#include <hip/hip_runtime.h>
#include <math.h>

typedef __bf16 bf16x8 __attribute__((ext_vector_type(8)));
typedef float f32x4 __attribute__((ext_vector_type(4)));

#define B_ 4
#define S_ 1024
#define D_ 768
#define F_ 3072
#define E_ 8
#define NTOK 4096
#define NSLOTP 9216   // 8192 slots + per-expert pad to 128

__device__ __forceinline__ void gload_lds16(const void* g, void* s) {
  __builtin_amdgcn_global_load_lds((const __attribute__((address_space(1))) void*)g,
                                   (__attribute__((address_space(3))) void*)s, 16, 0, 0);
}

template<int N> __device__ __forceinline__ void wait_vmcnt() {
  if constexpr (N == 0)      asm volatile("s_waitcnt vmcnt(0)" ::: "memory");
  else if constexpr (N == 3) asm volatile("s_waitcnt vmcnt(3)" ::: "memory");
  else if constexpr (N == 4) asm volatile("s_waitcnt vmcnt(4)" ::: "memory");
  else if constexpr (N == 6) asm volatile("s_waitcnt vmcnt(6)" ::: "memory");
  else if constexpr (N == 8) asm volatile("s_waitcnt vmcnt(8)" ::: "memory");
  else static_assert(N == 0, "unhandled vmcnt");
}
#define BAR()    asm volatile("s_barrier" ::: "memory")
#define LGKM0()  do { asm volatile("s_waitcnt lgkmcnt(0)" ::: "memory"); \
                      __builtin_amdgcn_sched_barrier(0); } while (0)

__device__ __forceinline__ float gelu_f(float v) {
  float u = v * (0.7978845608f + 0.0356774081f * v * v);
  float t = 1.f - 2.f / (1.f + __expf(2.f * u));   // tanh(u), correct +/-inf limits
  return 0.5f * v * (1.f + t);
}

// ---------------- router: fp32 logits, softmax, top-2, renorm (NO atomics) ----------------
__global__ __launch_bounds__(256) void k_router(const float* __restrict__ x,
    const float* __restrict__ wr, int* __restrict__ tki, float* __restrict__ tkw) {
  int wid = threadIdx.x >> 6, lane = threadIdx.x & 63;
  int t = blockIdx.x * 4 + wid;
  const float* xp = x + (size_t)t * D_;
  float pa[E_];
#pragma unroll
  for (int e = 0; e < E_; ++e) pa[e] = 0.f;
#pragma unroll
  for (int it = 0; it < D_ / 64; ++it) {
    int d = it * 64 + lane;
    float xv = xp[d];
    const float4* wp = (const float4*)(wr + (size_t)d * E_);
    float4 a = wp[0], b = wp[1];
    pa[0] += xv * a.x; pa[1] += xv * a.y; pa[2] += xv * a.z; pa[3] += xv * a.w;
    pa[4] += xv * b.x; pa[5] += xv * b.y; pa[6] += xv * b.z; pa[7] += xv * b.w;
  }
#pragma unroll
  for (int e = 0; e < E_; ++e) {
    float v = pa[e];
    for (int off = 32; off; off >>= 1) v += __shfl_xor(v, off);
    pa[e] = v;
  }
  if (lane == 0) {
    float m = pa[0];
#pragma unroll
    for (int e = 1; e < E_; ++e) m = fmaxf(m, pa[e]);
    float p[E_], s = 0.f;
#pragma unroll
    for (int e = 0; e < E_; ++e) { p[e] = expf(pa[e] - m); s += p[e]; }
#pragma unroll
    for (int e = 0; e < E_; ++e) p[e] = p[e] / s;
    int i0 = 0; float b0 = p[0];
#pragma unroll
    for (int e = 1; e < E_; ++e) if (p[e] > b0) { b0 = p[e]; i0 = e; }
    int i1 = -1; float b1v = -1.f;
#pragma unroll
    for (int e = 0; e < E_; ++e) if (e != i0 && p[e] > b1v) { b1v = p[e]; i1 = e; }
    float den = b0 + b1v + 1e-8f;
    tki[t * 2] = i0; tki[t * 2 + 1] = i1;
    tkw[t * 2] = b0 / den; tkw[t * 2 + 1] = b1v / den;
  }
}

// ---- single-block routing: histogram -> scan -> 128-aligned offsets -> ordered slots ----
__global__ __launch_bounds__(256) void k_route_all(const int* __restrict__ tki,
    int* __restrict__ stok, int* __restrict__ tslot, int* __restrict__ aoff) {
  __shared__ int cl[256][E_];
  __shared__ int tot[E_];
  __shared__ int aoffA[E_ + 1];
  int tid = threadIdx.x;
  for (int i = tid; i < NSLOTP; i += 256) stok[i] = -1;
#pragma unroll
  for (int e = 0; e < E_; ++e) cl[tid][e] = 0;
  int t0 = tid * (NTOK / 256);
#pragma unroll
  for (int i = 0; i < NTOK / 256; ++i) {
    cl[tid][tki[(t0 + i) * 2]]++;
    cl[tid][tki[(t0 + i) * 2 + 1]]++;
  }
  __syncthreads();
  if (tid < E_) {
    int run = 0;
    for (int i = 0; i < 256; ++i) { int v = cl[i][tid]; cl[i][tid] = run; run += v; }
    tot[tid] = run;
  }
  __syncthreads();
  if (tid == 0) {
    int a = 0; aoffA[0] = 0; aoff[0] = 0;
    for (int e = 0; e < E_; ++e) { a += ((tot[e] + 127) >> 7) << 7; aoffA[e + 1] = a; aoff[e + 1] = a; }
  }
  __syncthreads();
#pragma unroll
  for (int i = 0; i < NTOK / 256; ++i) {
    int t = t0 + i;
#pragma unroll
    for (int k = 0; k < 2; ++k) {
      int e = tki[t * 2 + k];
      int pos = aoffA[e] + cl[tid][e];
      cl[tid][e]++;
      stok[pos] = t;
      tslot[t * 2 + k] = pos;
    }
  }
}

// -------- gather x rows into bf16 slot matrix (zeros for padding) --------
__global__ __launch_bounds__(256) void k_gather(const float* __restrict__ x,
    const int* __restrict__ stok, __bf16* __restrict__ Xg) {
  int i8 = blockIdx.x * 256 + threadIdx.x;
  int flat = i8 * 8;
  int row = flat / D_;
  int col = flat - row * D_;
  int tok = stok[row];
  bf16x8 v;
  if (tok >= 0) {
    const float4* s = (const float4*)(x + (size_t)tok * D_ + col);
    float4 a = s[0], b = s[1];
    v[0] = (__bf16)a.x; v[1] = (__bf16)a.y; v[2] = (__bf16)a.z; v[3] = (__bf16)a.w;
    v[4] = (__bf16)b.x; v[5] = (__bf16)b.y; v[6] = (__bf16)b.z; v[7] = (__bf16)b.w;
  } else {
#pragma unroll
    for (int k = 0; k < 8; ++k) v[k] = (__bf16)0.f;
  }
  *(bf16x8*)(Xg + (size_t)flat) = v;
}

// -------- fp32 [R][C] -> bf16 [C][R] per expert --------
__global__ __launch_bounds__(256) void k_transpose(const float* __restrict__ in,
    __bf16* __restrict__ outp, int R, int C) {
  __shared__ float Ts[64][65];
  int e = blockIdx.z;
  int r0 = blockIdx.y * 64, c0 = blockIdx.x * 64;
  const float* ip = in + (size_t)e * R * C;
  int lr = threadIdx.x >> 4;
  int lc = (threadIdx.x & 15) * 4;
#pragma unroll
  for (int it = 0; it < 4; ++it) {
    int r = lr + it * 16;
    float4 v = *(const float4*)(ip + (size_t)(r0 + r) * C + c0 + lc);
    Ts[r][lc] = v.x; Ts[r][lc + 1] = v.y; Ts[r][lc + 2] = v.z; Ts[r][lc + 3] = v.w;
  }
  __syncthreads();
  int rr = (threadIdx.x & 7) * 8;
  int cc = threadIdx.x >> 3;
  __bf16* op = outp + (size_t)e * R * C + r0 + rr;
#pragma unroll
  for (int it = 0; it < 2; ++it) {
    int c = cc + it * 32;
    bf16x8 v;
#pragma unroll
    for (int i = 0; i < 8; ++i) v[i] = (__bf16)Ts[rr + i][c];
    *(bf16x8*)(op + (size_t)(c0 + c) * R) = v;
  }
}

// ===== grouped GEMM: 4-buffer pipeline, counted vmcnt (T3+T4), setprio (T5) =====
// BM rows (expert-128-aligned), BK=32, WMxWN waves, per-wave (BM/WM)x(BN/WN).
// MODE 0: H = gelu(Xg @ w1t^T + b1).  MODE 1: Eout = H @ w2t^T + b2 (fp32).
template<int KST, int N, int BM, int BN, int WM, int WN, int MODE>
__global__ __launch_bounds__(WM * WN * 64, 2) void k_gemm(
    const __bf16* __restrict__ A, const __bf16* __restrict__ Bt,
    const float* __restrict__ bias, const int* __restrict__ aoff,
    __bf16* __restrict__ Hout, float* __restrict__ Eout) {
  constexpr int NW = WM * WN;
  constexpr int THREADS = NW * 64;
  constexpr int LA = (BM * 4) / THREADS;   // A gload instrs per wave per tile
  constexpr int LB = (BN * 4) / THREADS;
  constexpr int L = LA + LB;
  constexpr int ASZ = BM * 32;             // elems per buffer
  constexpr int BSZ = BN * 32;
  constexpr int PWM = BM / WM, PWN = BN / WN;
  constexpr int MI = PWM / 16, NJ = PWN / 16, MH = MI / 2;
  constexpr int NK = KST / 32;
  constexpr int NB = N / BN, NMB = NSLOTP / BM, NWG = NB * NMB;

  __shared__ __align__(16) __bf16 Als[4 * ASZ];
  __shared__ __align__(16) __bf16 Bls[4 * BSZ];

  int bswz = (blockIdx.x & 7) * (NWG / 8) + (blockIdx.x >> 3);   // XCD-bijective (NWG%8==0)
  int mb = bswz % NMB, nb = bswz / NMB;                          // mb-fast: B panel stays hot
  int row0 = mb * BM;
  if (row0 >= aoff[E_]) return;
  int e = 0;
#pragma unroll
  for (int q = 0; q < E_; ++q) if (row0 >= aoff[q + 1]) e = q + 1;
  const __bf16* Bp = Bt + (size_t)e * D_ * F_;

  int tid = threadIdx.x, w = tid >> 6, l = tid & 63;
  int lr = l >> 2, ls = l & 3;      // staging lane -> row-in-16 / 16B slot
  int fr = l & 15, fg = l >> 4;     // fragment lane -> row / k-group
  int wr = w / WN, wc = w % WN;

  auto STAGE_A = [&](int kt, int b) {
#pragma unroll
    for (int q = 0; q < LA; ++q) {
      int idx = w * LA + q;
      int row = idx * 16 + lr;
      int slot = ls ^ ((row >> 1) & 3);
      gload_lds16(A + (size_t)(row0 + row) * KST + kt * 32 + slot * 8,
                  Als + b * ASZ + idx * 512);
    }
  };
  auto STAGE_B = [&](int kt, int b) {
#pragma unroll
    for (int q = 0; q < LB; ++q) {
      int idx = w * LB + q;
      int row = idx * 16 + lr;
      int slot = ls ^ ((row >> 1) & 3);
      gload_lds16(Bp + (size_t)(nb * BN + row) * KST + kt * 32 + slot * 8,
                  Bls + b * BSZ + idx * 512);
    }
  };

  // prologue: stage tiles 0,1,2; drain tile 0 (leave 2L in flight)
  STAGE_A(0, 0); STAGE_B(0, 0);
  STAGE_A(1, 1); STAGE_B(1, 1);
  STAGE_A(2, 2); STAGE_B(2, 2);
  wait_vmcnt<2 * L>();
  BAR();
  __builtin_amdgcn_sched_barrier(0);

  f32x4 acc[MI][NJ] = {};
  for (int t = 0; t < NK; ++t) {
    int b = t & 3, bs = (t + 3) & 3;
    bool st = (t + 3) < NK;
    // ---- phase 0: A-half 0 + all B frags; stage A(t+3) ----
    bf16x8 a0[MH], bfr[NJ];
#pragma unroll
    for (int i = 0; i < MH; ++i) {
      int r = wr * PWM + i * 16 + fr;
      a0[i] = *(const bf16x8*)(Als + b * ASZ + r * 32 + ((fg ^ ((r >> 1) & 3)) << 3));
    }
#pragma unroll
    for (int j = 0; j < NJ; ++j) {
      int n = wc * PWN + j * 16 + fr;
      bfr[j] = *(const bf16x8*)(Bls + b * BSZ + n * 32 + ((fg ^ ((n >> 1) & 3)) << 3));
    }
    if (st) STAGE_A(t + 3, bs);
    BAR();
    LGKM0();
    __builtin_amdgcn_s_setprio(1);
#pragma unroll
    for (int i = 0; i < MH; ++i)
#pragma unroll
      for (int j = 0; j < NJ; ++j)
        acc[i][j] = __builtin_amdgcn_mfma_f32_16x16x32_bf16(a0[i], bfr[j], acc[i][j], 0, 0, 0);
    __builtin_amdgcn_s_setprio(0);
    __builtin_amdgcn_sched_barrier(0);
    BAR();
    // ---- phase 1: A-half 1 (B frags held in regs); stage B(t+3); counted vmcnt ----
    bf16x8 a1[MH];
#pragma unroll
    for (int i = 0; i < MH; ++i) {
      int r = wr * PWM + (MH + i) * 16 + fr;
      a1[i] = *(const bf16x8*)(Als + b * ASZ + r * 32 + ((fg ^ ((r >> 1) & 3)) << 3));
    }
    if (st) STAGE_B(t + 3, bs);
    if (st)                 wait_vmcnt<2 * L>();   // drains tile t+1; t+2,t+3 stay in flight
    else if (t + 2 < NK)    wait_vmcnt<L>();
    else if (t + 1 < NK)    wait_vmcnt<0>();
    BAR();
    LGKM0();
    __builtin_amdgcn_s_setprio(1);
#pragma unroll
    for (int i = 0; i < MH; ++i)
#pragma unroll
      for (int j = 0; j < NJ; ++j)
        acc[MH + i][j] = __builtin_amdgcn_mfma_f32_16x16x32_bf16(a1[i], bfr[j], acc[MH + i][j], 0, 0, 0);
    __builtin_amdgcn_s_setprio(0);
    __builtin_amdgcn_sched_barrier(0);
    BAR();
  }

  if constexpr (MODE == 0) {
#pragma unroll
    for (int j = 0; j < NJ; ++j) {
      int col = nb * BN + wc * PWN + j * 16 + fr;
      float bv = bias[e * N + col];
#pragma unroll
      for (int i = 0; i < MI; ++i) {
#pragma unroll
        for (int r = 0; r < 4; ++r) {
          int row = row0 + wr * PWM + i * 16 + fg * 4 + r;
          Hout[(size_t)row * N + col] = (__bf16)gelu_f(acc[i][j][r] + bv);
        }
      }
    }
  } else {
#pragma unroll
    for (int j = 0; j < NJ; ++j) {
      int col = nb * BN + wc * PWN + j * 16 + fr;
      float bv = bias[e * N + col];
#pragma unroll
      for (int i = 0; i < MI; ++i) {
#pragma unroll
        for (int r = 0; r < 4; ++r) {
          int row = row0 + wr * PWM + i * 16 + fg * 4 + r;
          Eout[(size_t)row * N + col] = acc[i][j][r] + bv;
        }
      }
    }
  }
}

// -------- combine: out[t] = w0*Eout[s0] + w1*Eout[s1] --------
__global__ __launch_bounds__(256) void k_combine(const float* __restrict__ Eout,
    const int* __restrict__ tslot, const float* __restrict__ tkw, float* __restrict__ out) {
  int idx = blockIdx.x * 256 + threadIdx.x;
  int t = idx / (D_ / 4);
  int c4 = (idx - t * (D_ / 4)) * 4;
  int s0 = tslot[2 * t], s1 = tslot[2 * t + 1];
  float w0 = tkw[2 * t], w1 = tkw[2 * t + 1];
  float4 a = *(const float4*)(Eout + (size_t)s0 * D_ + c4);
  float4 b = *(const float4*)(Eout + (size_t)s1 * D_ + c4);
  float4 o;
  o.x = w0 * a.x + w1 * b.x; o.y = w0 * a.y + w1 * b.y;
  o.z = w0 * a.z + w1 * b.z; o.w = w0 * a.w + w1 * b.w;
  *(float4*)(out + (size_t)t * D_ + c4) = o;
}

extern "C" void kernel_launch(void* const* d_in, const int* in_sizes, int n_in,
                              void* d_out, int out_size, void* d_ws, size_t ws_size,
                              hipStream_t stream) {
  const float* x  = (const float*)d_in[0];
  const float* wr = (const float*)d_in[1];
  const float* w1 = (const float*)d_in[2];
  const float* b1 = (const float*)d_in[3];
  const float* w2 = (const float*)d_in[4];
  const float* b2 = (const float*)d_in[5];
  float* out = (float*)d_out;

  char* ws = (char*)d_ws;
  size_t o = 0;
  __bf16* w1t = (__bf16*)(ws + o); o += (size_t)E_ * D_ * F_ * 2;   // dead after GEMM1
  __bf16* Xg  = (__bf16*)(ws + o); o += (size_t)NSLOTP * D_ * 2;    // dead after GEMM1
  __bf16* w2t = (__bf16*)(ws + o); o += (size_t)E_ * D_ * F_ * 2;
  __bf16* H   = (__bf16*)(ws + o); o += (size_t)NSLOTP * F_ * 2;
  int*   tki  = (int*)(ws + o);   o += (size_t)NTOK * 2 * 4;
  float* tkw  = (float*)(ws + o); o += (size_t)NTOK * 2 * 4;
  int*   stok = (int*)(ws + o);   o += (size_t)NSLOTP * 4;
  int*   tslot= (int*)(ws + o);   o += (size_t)NTOK * 2 * 4;
  int*   aoff = (int*)(ws + o);   o += 64;
  float* Eout = (float*)w1t;      // alias: 28.3MB fits in dead w1t (37.7MB)
  if (ws_size < o) return;

  k_router<<<NTOK / 4, 256, 0, stream>>>(x, wr, tki, tkw);
  k_route_all<<<1, 256, 0, stream>>>(tki, stok, tslot, aoff);
  k_gather<<<(NSLOTP * D_ / 8) / 256, 256, 0, stream>>>(x, stok, Xg);
  k_transpose<<<dim3(F_ / 64, D_ / 64, E_), 256, 0, stream>>>(w1, w1t, D_, F_);
  k_transpose<<<dim3(D_ / 64, F_ / 64, E_), 256, 0, stream>>>(w2, w2t, F_, D_);
  // GEMM1: 128x256 tile, 8 waves (2x4), per-wave 64x64.  12*72 = 864 blocks.
  k_gemm<D_, F_, 128, 256, 2, 4, 0><<<(F_ / 256) * (NSLOTP / 128), 512, 0, stream>>>(
      Xg, w1t, b1, aoff, H, nullptr);
  // GEMM2: 128x128 tile, 4 waves (2x2), per-wave 64x64, 64KB LDS -> 2 blocks/CU. 432 blocks.
  k_gemm<F_, D_, 128, 128, 2, 2, 1><<<(D_ / 128) * (NSLOTP / 128), 256, 0, stream>>>(
      H, w2t, b2, aoff, nullptr, Eout);
  k_combine<<<NTOK * (D_ / 4) / 256, 256, 0, stream>>>(Eout, tslot, tkw, out);
}

// Round 7
// 227.390 us; speedup vs baseline: 1.1030x; 1.1030x over previous
//
#include <hip/hip_runtime.h>
#include <math.h>

typedef __bf16 bf16x8 __attribute__((ext_vector_type(8)));
typedef float f32x4 __attribute__((ext_vector_type(4)));

#define B_ 4
#define S_ 1024
#define D_ 768
#define F_ 3072
#define E_ 8
#define NTOK 4096
#define NSLOTP 9216   // 8192 slots + per-expert pad to 128

__device__ __forceinline__ void gload_lds16(const void* g, void* s) {
  __builtin_amdgcn_global_load_lds((const __attribute__((address_space(1))) void*)g,
                                   (__attribute__((address_space(3))) void*)s, 16, 0, 0);
}

template<int N> __device__ __forceinline__ void wait_vmcnt() {
  if constexpr (N == 0)      asm volatile("s_waitcnt vmcnt(0)" ::: "memory");
  else if constexpr (N == 6) asm volatile("s_waitcnt vmcnt(6)" ::: "memory");
  else static_assert(N == 0, "unhandled vmcnt");
}
#define BAR()    asm volatile("s_barrier" ::: "memory")
#define LGKM0()  do { asm volatile("s_waitcnt lgkmcnt(0)" ::: "memory"); \
                      __builtin_amdgcn_sched_barrier(0); } while (0)

__device__ __forceinline__ float gelu_f(float v) {
  float u = v * (0.7978845608f + 0.0356774081f * v * v);
  float t = 1.f - 2.f / (1.f + __expf(2.f * u));   // tanh(u), correct +/-inf limits
  return 0.5f * v * (1.f + t);
}

// ---------------- router: fp32 logits, softmax, top-2, renorm (NO atomics) ----------------
__global__ __launch_bounds__(256) void k_router(const float* __restrict__ x,
    const float* __restrict__ wr, int* __restrict__ tki, float* __restrict__ tkw) {
  int wid = threadIdx.x >> 6, lane = threadIdx.x & 63;
  int t = blockIdx.x * 4 + wid;
  const float* xp = x + (size_t)t * D_;
  float pa[E_];
#pragma unroll
  for (int e = 0; e < E_; ++e) pa[e] = 0.f;
#pragma unroll
  for (int it = 0; it < D_ / 64; ++it) {
    int d = it * 64 + lane;
    float xv = xp[d];
    const float4* wp = (const float4*)(wr + (size_t)d * E_);
    float4 a = wp[0], b = wp[1];
    pa[0] += xv * a.x; pa[1] += xv * a.y; pa[2] += xv * a.z; pa[3] += xv * a.w;
    pa[4] += xv * b.x; pa[5] += xv * b.y; pa[6] += xv * b.z; pa[7] += xv * b.w;
  }
#pragma unroll
  for (int e = 0; e < E_; ++e) {
    float v = pa[e];
    for (int off = 32; off; off >>= 1) v += __shfl_xor(v, off);
    pa[e] = v;
  }
  if (lane == 0) {
    float m = pa[0];
#pragma unroll
    for (int e = 1; e < E_; ++e) m = fmaxf(m, pa[e]);
    float p[E_], s = 0.f;
#pragma unroll
    for (int e = 0; e < E_; ++e) { p[e] = expf(pa[e] - m); s += p[e]; }
#pragma unroll
    for (int e = 0; e < E_; ++e) p[e] = p[e] / s;
    int i0 = 0; float b0 = p[0];
#pragma unroll
    for (int e = 1; e < E_; ++e) if (p[e] > b0) { b0 = p[e]; i0 = e; }
    int i1 = -1; float b1v = -1.f;
#pragma unroll
    for (int e = 0; e < E_; ++e) if (e != i0 && p[e] > b1v) { b1v = p[e]; i1 = e; }
    float den = b0 + b1v + 1e-8f;
    tki[t * 2] = i0; tki[t * 2 + 1] = i1;
    tkw[t * 2] = b0 / den; tkw[t * 2 + 1] = b1v / den;
  }
}

// ---- single-block routing: histogram -> scan -> 128-aligned offsets -> ordered slots ----
__global__ __launch_bounds__(256) void k_route_all(const int* __restrict__ tki,
    int* __restrict__ stok, int* __restrict__ tslot, int* __restrict__ aoff) {
  __shared__ int cl[256][E_];
  __shared__ int tot[E_];
  __shared__ int aoffA[E_ + 1];
  int tid = threadIdx.x;
  for (int i = tid; i < NSLOTP; i += 256) stok[i] = -1;
#pragma unroll
  for (int e = 0; e < E_; ++e) cl[tid][e] = 0;
  int t0 = tid * (NTOK / 256);
#pragma unroll
  for (int i = 0; i < NTOK / 256; ++i) {
    cl[tid][tki[(t0 + i) * 2]]++;
    cl[tid][tki[(t0 + i) * 2 + 1]]++;
  }
  __syncthreads();
  if (tid < E_) {
    int run = 0;
    for (int i = 0; i < 256; ++i) { int v = cl[i][tid]; cl[i][tid] = run; run += v; }
    tot[tid] = run;
  }
  __syncthreads();
  if (tid == 0) {
    int a = 0; aoffA[0] = 0; aoff[0] = 0;
    for (int e = 0; e < E_; ++e) { a += ((tot[e] + 127) >> 7) << 7; aoffA[e + 1] = a; aoff[e + 1] = a; }
  }
  __syncthreads();
#pragma unroll
  for (int i = 0; i < NTOK / 256; ++i) {
    int t = t0 + i;
#pragma unroll
    for (int k = 0; k < 2; ++k) {
      int e = tki[t * 2 + k];
      int pos = aoffA[e] + cl[tid][e];
      cl[tid][e]++;
      stok[pos] = t;
      tslot[t * 2 + k] = pos;
    }
  }
}

// -------- gather x rows into bf16 slot matrix (zeros for padding) --------
__global__ __launch_bounds__(256) void k_gather(const float* __restrict__ x,
    const int* __restrict__ stok, __bf16* __restrict__ Xg) {
  int i8 = blockIdx.x * 256 + threadIdx.x;
  int flat = i8 * 8;
  int row = flat / D_;
  int col = flat - row * D_;
  int tok = stok[row];
  bf16x8 v;
  if (tok >= 0) {
    const float4* s = (const float4*)(x + (size_t)tok * D_ + col);
    float4 a = s[0], b = s[1];
    v[0] = (__bf16)a.x; v[1] = (__bf16)a.y; v[2] = (__bf16)a.z; v[3] = (__bf16)a.w;
    v[4] = (__bf16)b.x; v[5] = (__bf16)b.y; v[6] = (__bf16)b.z; v[7] = (__bf16)b.w;
  } else {
#pragma unroll
    for (int k = 0; k < 8; ++k) v[k] = (__bf16)0.f;
  }
  *(bf16x8*)(Xg + (size_t)flat) = v;
}

// -------- fp32 [R][C] -> bf16 [C][R] per expert --------
__global__ __launch_bounds__(256) void k_transpose(const float* __restrict__ in,
    __bf16* __restrict__ outp, int R, int C) {
  __shared__ float Ts[64][65];
  int e = blockIdx.z;
  int r0 = blockIdx.y * 64, c0 = blockIdx.x * 64;
  const float* ip = in + (size_t)e * R * C;
  int lr = threadIdx.x >> 4;
  int lc = (threadIdx.x & 15) * 4;
#pragma unroll
  for (int it = 0; it < 4; ++it) {
    int r = lr + it * 16;
    float4 v = *(const float4*)(ip + (size_t)(r0 + r) * C + c0 + lc);
    Ts[r][lc] = v.x; Ts[r][lc + 1] = v.y; Ts[r][lc + 2] = v.z; Ts[r][lc + 3] = v.w;
  }
  __syncthreads();
  int rr = (threadIdx.x & 7) * 8;
  int cc = threadIdx.x >> 3;
  __bf16* op = outp + (size_t)e * R * C + r0 + rr;
#pragma unroll
  for (int it = 0; it < 2; ++it) {
    int c = cc + it * 32;
    bf16x8 v;
#pragma unroll
    for (int i = 0; i < 8; ++i) v[i] = (__bf16)Ts[rr + i][c];
    *(bf16x8*)(op + (size_t)(c0 + c) * R) = v;
  }
}

// ===== GEMM1: m201-style fine phases. BM=128, BN=256, BK=64, 8 waves (2x4), =====
// ===== tri-buffer LDS (144KB), vmcnt(6) once per K-tile, A-frags cached.     =====
// H = gelu(Xg @ w1t^T + b1)
__global__ __launch_bounds__(512, 1) void k_gemm1(
    const __bf16* __restrict__ A, const __bf16* __restrict__ Bt,
    const float* __restrict__ bias, const int* __restrict__ aoff,
    __bf16* __restrict__ Hout) {
  constexpr int KST = D_;                 // 768
  constexpr int N = F_;                   // 3072
  constexpr int NK = KST / 64;            // 12 K-tiles
  constexpr int ASZ = 128 * 64;           // elems per A buffer
  constexpr int BSZ = 256 * 64;
  constexpr int NB = N / 256, NMB = NSLOTP / 128, NWG = NB * NMB;   // 12*72=864

  __shared__ __align__(16) __bf16 Als[3 * ASZ];   // 48KB
  __shared__ __align__(16) __bf16 Bls[3 * BSZ];   // 96KB

  int bswz = (blockIdx.x & 7) * (NWG / 8) + (blockIdx.x >> 3);   // XCD-bijective
  int mb = bswz % NMB, nb = bswz / NMB;                          // mb-fast: B panel L2-hot
  int row0 = mb * 128;
  if (row0 >= aoff[E_]) return;
  int e = 0;
#pragma unroll
  for (int q = 0; q < E_; ++q) if (row0 >= aoff[q + 1]) e = q + 1;
  const __bf16* Bp = Bt + (size_t)e * D_ * F_;

  int tid = threadIdx.x, w = tid >> 6, l = tid & 63;
  int fr = l & 15, fg = l >> 4;           // fragment lane -> row / k-group
  int wr = w >> 2, wc = w & 3;            // 2M x 4N waves, per-wave 64x64

  // staging decomposition: unit = 512thr x 16B = 8KB = 64 rows x 128B
  int ur = tid >> 3;                      // row within unit (0..63)
  int us = tid & 7;                       // 16B slot within row (0..7)
  int ukk = us >> 2, uf4 = us & 3;        // k-half, quarter-slot

  // A tile (128x64) = units 0..1; B tile (256x64) = units 0..3
  auto SA = [&](int kt, int b) {
#pragma unroll
    for (int u = 0; u < 2; ++u) {
      int r = u * 64 + ur;
      int f4s = uf4 ^ ((r >> 1) & 3);
      gload_lds16(A + (size_t)(row0 + r) * KST + kt * 64 + ukk * 32 + f4s * 8,
                  Als + b * ASZ + u * 4096 + w * 512);
    }
  };
  auto SB = [&](int kt, int b, int u0, int u1) {
    for (int u = u0; u < u1; ++u) {
      int r = u * 64 + ur;
      int f4s = uf4 ^ ((r >> 1) & 3);
      gload_lds16(Bp + (size_t)(nb * 256 + r) * KST + kt * 64 + ukk * 32 + f4s * 8,
                  Bls + b * BSZ + u * 4096 + w * 512);
    }
  };

  // prologue: stage tiles 0 and 1 fully (12 loads/thread in flight)
  SA(0, 0); SB(0, 0, 0, 4);
  SA(1, 1); SB(1, 1, 0, 4);

  f32x4 acc[4][4] = {};
  for (int t = 0; t < NK; ++t) {
    int b = t % 3, bs = (t + 2) % 3;
    bool st = (t + 2) < NK;
    // entry: drain tile t (leave tile t+1's 6 in flight), sync
    if (t + 1 < NK) wait_vmcnt<6>(); else wait_vmcnt<0>();
    BAR();
    __builtin_amdgcn_sched_barrier(0);
    const __bf16* Ab = Als + b * ASZ;
    const __bf16* Bb = Bls + b * BSZ;
    // ---- phase 0: read all A frags + B cols 0-1; stage A(t+2)+B(t+2) units 0-1 ----
    bf16x8 af[4][2], bf0[2][2];
#pragma unroll
    for (int i = 0; i < 4; ++i) {
      int r = wr * 64 + i * 16 + fr;
      int sw = ((r >> 1) & 3);
#pragma unroll
      for (int kk = 0; kk < 2; ++kk)
        af[i][kk] = *(const bf16x8*)(Ab + r * 64 + kk * 32 + ((fg ^ sw) << 3));
    }
#pragma unroll
    for (int j = 0; j < 2; ++j) {
      int n = wc * 64 + j * 16 + fr;
      int sw = ((n >> 1) & 3);
#pragma unroll
      for (int kk = 0; kk < 2; ++kk)
        bf0[j][kk] = *(const bf16x8*)(Bb + n * 64 + kk * 32 + ((fg ^ sw) << 3));
    }
    if (st) { SA(t + 2, bs); SB(t + 2, bs, 0, 2); }
    LGKM0();
    __builtin_amdgcn_s_setprio(1);
#pragma unroll
    for (int i = 0; i < 4; ++i)
#pragma unroll
      for (int j = 0; j < 2; ++j)
#pragma unroll
        for (int kk = 0; kk < 2; ++kk)
          acc[i][j] = __builtin_amdgcn_mfma_f32_16x16x32_bf16(af[i][kk], bf0[j][kk], acc[i][j], 0, 0, 0);
    __builtin_amdgcn_s_setprio(0);
    __builtin_amdgcn_sched_barrier(0);
    BAR();
    // ---- phase 1: read B cols 2-3 (A cached); stage B(t+2) units 2-3 ----
    bf16x8 bf1[2][2];
#pragma unroll
    for (int j = 0; j < 2; ++j) {
      int n = wc * 64 + (2 + j) * 16 + fr;
      int sw = ((n >> 1) & 3);
#pragma unroll
      for (int kk = 0; kk < 2; ++kk)
        bf1[j][kk] = *(const bf16x8*)(Bb + n * 64 + kk * 32 + ((fg ^ sw) << 3));
    }
    if (st) SB(t + 2, bs, 2, 4);
    LGKM0();
    __builtin_amdgcn_s_setprio(1);
#pragma unroll
    for (int i = 0; i < 4; ++i)
#pragma unroll
      for (int j = 0; j < 2; ++j)
#pragma unroll
        for (int kk = 0; kk < 2; ++kk)
          acc[i][2 + j] = __builtin_amdgcn_mfma_f32_16x16x32_bf16(af[i][kk], bf1[j][kk], acc[i][2 + j], 0, 0, 0);
    __builtin_amdgcn_s_setprio(0);
    __builtin_amdgcn_sched_barrier(0);
  }

#pragma unroll
  for (int j = 0; j < 4; ++j) {
    int col = nb * 256 + wc * 64 + j * 16 + fr;
    float bv = bias[e * N + col];
#pragma unroll
    for (int i = 0; i < 4; ++i) {
#pragma unroll
      for (int r = 0; r < 4; ++r) {
        int row = row0 + wr * 64 + i * 16 + fg * 4 + r;
        Hout[(size_t)row * N + col] = (__bf16)gelu_f(acc[i][j][r] + bv);
      }
    }
  }
}

// ===== GEMM2 (round-5 proven): 2-phase double-buffer, BM=128, BN=256, BK=32 =====
// MODE 1: E[kh] = H[:,khalf] @ w2t[:,khalf]^T (+b2 if kh==0).
template<int KST, int N, int KSPLIT>
__global__ __launch_bounds__(512, 4) void k_gemm2(
    const __bf16* __restrict__ A, const __bf16* __restrict__ Bt,
    const float* __restrict__ bias, const int* __restrict__ aoff,
    float* __restrict__ E0, float* __restrict__ E1) {
  constexpr int BN = 256;
  constexpr int ASZ = 128 * 32;
  constexpr int BSZ = BN * 32;
  constexpr int NK = KST / 32 / KSPLIT;
  constexpr int NB = N / BN;
  constexpr int NMB = NSLOTP / 128;
  constexpr int NWGB = NB * NMB;
  constexpr int NWG = NWGB * KSPLIT;

  __shared__ __align__(16) __bf16 Als[2 * ASZ];
  __shared__ __align__(16) __bf16 Bls[2 * BSZ];

  int bswz = (blockIdx.x & 7) * (NWG / 8) + (blockIdx.x >> 3);
  int kh = bswz / NWGB;
  int rem = bswz % NWGB;
  int mb = rem % NMB, nb = rem / NMB;
  int row0 = mb * 128;
  if (row0 >= aoff[E_]) return;
  int e = 0;
#pragma unroll
  for (int q = 0; q < E_; ++q) if (row0 >= aoff[q + 1]) e = q + 1;
  const __bf16* Bp = Bt + (size_t)e * D_ * F_;
  int kbase = kh * (KST / KSPLIT);

  int tid = threadIdx.x, w = tid >> 6, l = tid & 63;
  int lr = l >> 2, ls = l & 3;
  int fr = l & 15, fg = l >> 4;
  int wrow = (w >> 2) * 64, wcol = (w & 3) * 64;

  auto STAGE = [&](int kt, int b) {
    int k0 = kbase + kt * 32;
    {
      int rowA = w * 16 + lr;
      int sA = ls ^ ((rowA >> 1) & 3);
      gload_lds16(A + (size_t)(row0 + rowA) * KST + k0 + sA * 8, Als + b * ASZ + w * 512);
    }
#pragma unroll
    for (int q = 0; q < 2; ++q) {
      int idx = w * 2 + q;
      int rowB = idx * 16 + lr;
      int sB = ls ^ ((rowB >> 1) & 3);
      gload_lds16(Bp + (size_t)(nb * BN + rowB) * KST + k0 + sB * 8, Bls + b * BSZ + idx * 512);
    }
  };

  f32x4 acc[4][4] = {};
  STAGE(0, 0);
  asm volatile("s_waitcnt vmcnt(0)" ::: "memory");
  __builtin_amdgcn_sched_barrier(0);
  __builtin_amdgcn_s_barrier();
  for (int t = 0; t < NK; ++t) {
    int cur = t & 1;
    if (t + 1 < NK) STAGE(t + 1, cur ^ 1);
    __builtin_amdgcn_sched_barrier(0);
    bf16x8 af[4], bfr[4];
#pragma unroll
    for (int i = 0; i < 4; ++i) {
      int rl = wrow + i * 16 + fr;
      af[i] = *(const bf16x8*)(Als + cur * ASZ + rl * 32 + ((fg ^ ((rl >> 1) & 3)) << 3));
    }
#pragma unroll
    for (int j = 0; j < 4; ++j) {
      int nl = wcol + j * 16 + fr;
      bfr[j] = *(const bf16x8*)(Bls + cur * BSZ + nl * 32 + ((fg ^ ((nl >> 1) & 3)) << 3));
    }
#pragma unroll
    for (int i = 0; i < 4; ++i)
#pragma unroll
      for (int j = 0; j < 4; ++j)
        acc[i][j] = __builtin_amdgcn_mfma_f32_16x16x32_bf16(af[i], bfr[j], acc[i][j], 0, 0, 0);
    __builtin_amdgcn_sched_barrier(0);
    asm volatile("s_waitcnt vmcnt(0)" ::: "memory");
    __builtin_amdgcn_s_barrier();
  }

  float* Ep = (kh == 0) ? E0 : E1;
#pragma unroll
  for (int j = 0; j < 4; ++j) {
    int col = nb * BN + wcol + j * 16 + fr;
    float bv = (kh == 0) ? bias[e * N + col] : 0.f;
#pragma unroll
    for (int i = 0; i < 4; ++i) {
#pragma unroll
      for (int r = 0; r < 4; ++r) {
        int row = row0 + wrow + i * 16 + fg * 4 + r;
        Ep[(size_t)row * N + col] = acc[i][j][r] + bv;
      }
    }
  }
}

// -------- combine: out[t] = w0*(E0+E1)[s0] + w1*(E0+E1)[s1] --------
__global__ __launch_bounds__(256) void k_combine(const float* __restrict__ E0,
    const float* __restrict__ E1, const int* __restrict__ tslot,
    const float* __restrict__ tkw, float* __restrict__ out) {
  int idx = blockIdx.x * 256 + threadIdx.x;
  int t = idx / (D_ / 4);
  int c4 = (idx - t * (D_ / 4)) * 4;
  int s0 = tslot[2 * t], s1 = tslot[2 * t + 1];
  float w0 = tkw[2 * t], w1 = tkw[2 * t + 1];
  float4 a = *(const float4*)(E0 + (size_t)s0 * D_ + c4);
  float4 b = *(const float4*)(E0 + (size_t)s1 * D_ + c4);
  float4 o;
  if (E1) {
    float4 a1 = *(const float4*)(E1 + (size_t)s0 * D_ + c4);
    float4 b1 = *(const float4*)(E1 + (size_t)s1 * D_ + c4);
    o.x = w0 * (a.x + a1.x) + w1 * (b.x + b1.x);
    o.y = w0 * (a.y + a1.y) + w1 * (b.y + b1.y);
    o.z = w0 * (a.z + a1.z) + w1 * (b.z + b1.z);
    o.w = w0 * (a.w + a1.w) + w1 * (b.w + b1.w);
  } else {
    o.x = w0 * a.x + w1 * b.x; o.y = w0 * a.y + w1 * b.y;
    o.z = w0 * a.z + w1 * b.z; o.w = w0 * a.w + w1 * b.w;
  }
  *(float4*)(out + (size_t)t * D_ + c4) = o;
}

extern "C" void kernel_launch(void* const* d_in, const int* in_sizes, int n_in,
                              void* d_out, int out_size, void* d_ws, size_t ws_size,
                              hipStream_t stream) {
  const float* x  = (const float*)d_in[0];
  const float* wr = (const float*)d_in[1];
  const float* w1 = (const float*)d_in[2];
  const float* b1 = (const float*)d_in[3];
  const float* w2 = (const float*)d_in[4];
  const float* b2 = (const float*)d_in[5];
  float* out = (float*)d_out;

  char* ws = (char*)d_ws;
  size_t o = 0;
  __bf16* w1t = (__bf16*)(ws + o); o += (size_t)E_ * D_ * F_ * 2;   // dead after GEMM1
  __bf16* Xg  = (__bf16*)(ws + o); o += (size_t)NSLOTP * D_ * 2;    // dead after GEMM1
  __bf16* w2t = (__bf16*)(ws + o); o += (size_t)E_ * D_ * F_ * 2;
  __bf16* H   = (__bf16*)(ws + o); o += (size_t)NSLOTP * F_ * 2;
  int*   tki  = (int*)(ws + o);   o += (size_t)NTOK * 2 * 4;
  float* tkw  = (float*)(ws + o); o += (size_t)NTOK * 2 * 4;
  int*   stok = (int*)(ws + o);   o += (size_t)NSLOTP * 4;
  int*   tslot= (int*)(ws + o);   o += (size_t)NTOK * 2 * 4;
  int*   aoff = (int*)(ws + o);   o += 64;
  float* E0   = (float*)w1t;      // alias: 28.3MB fits in dead w1t (37.7MB)
  float* E1   = (float*)(ws + o); // tail partial buffer, used only if ws allows
  size_t oE1  = o + (size_t)NSLOTP * D_ * 4;
  if (ws_size < o) return;
  bool split = (ws_size >= oE1);

  k_router<<<NTOK / 4, 256, 0, stream>>>(x, wr, tki, tkw);
  k_route_all<<<1, 256, 0, stream>>>(tki, stok, tslot, aoff);
  k_gather<<<(NSLOTP * D_ / 8) / 256, 256, 0, stream>>>(x, stok, Xg);
  k_transpose<<<dim3(F_ / 64, D_ / 64, E_), 256, 0, stream>>>(w1, w1t, D_, F_);
  k_transpose<<<dim3(D_ / 64, F_ / 64, E_), 256, 0, stream>>>(w2, w2t, F_, D_);
  // GEMM1: fine-phase tri-buffer, 12*72 = 864 blocks
  k_gemm1<<<(F_ / 256) * (NSLOTP / 128), 512, 0, stream>>>(Xg, w1t, b1, aoff, H);
  // GEMM2: K=3072, N=768, split-K=2 -> 432 blocks (fallback: 216)
  if (split) {
    k_gemm2<F_, D_, 2><<<2 * (D_ / 256) * (NSLOTP / 128), 512, 0, stream>>>(
        H, w2t, b2, aoff, E0, E1);
    k_combine<<<NTOK * (D_ / 4) / 256, 256, 0, stream>>>(E0, E1, tslot, tkw, out);
  } else {
    k_gemm2<F_, D_, 1><<<(D_ / 256) * (NSLOTP / 128), 512, 0, stream>>>(
        H, w2t, b2, aoff, E0, nullptr);
    k_combine<<<NTOK * (D_ / 4) / 256, 256, 0, stream>>>(E0, nullptr, tslot, tkw, out);
  }
}

// Round 9
// 214.151 us; speedup vs baseline: 1.1712x; 1.0618x over previous
//
#include <hip/hip_runtime.h>
#include <math.h>

typedef __bf16 bf16x8 __attribute__((ext_vector_type(8)));
typedef float f32x4 __attribute__((ext_vector_type(4)));
typedef _Float16 f16;
typedef _Float16 f16x8 __attribute__((ext_vector_type(8)));

#define B_ 4
#define S_ 1024
#define D_ 768
#define F_ 3072
#define E_ 8
#define NTOK 4096
#define NSLOTP 10240   // 8192 slots + per-expert pad to 256

__device__ __forceinline__ void gload_lds16(const void* g, void* s) {
  __builtin_amdgcn_global_load_lds((const __attribute__((address_space(1))) void*)g,
                                   (__attribute__((address_space(3))) void*)s, 16, 0, 0);
}

template<int N> __device__ __forceinline__ void wait_vmcnt() {
  if constexpr (N == 0)      asm volatile("s_waitcnt vmcnt(0)" ::: "memory");
  else if constexpr (N == 4) asm volatile("s_waitcnt vmcnt(4)" ::: "memory");
  else static_assert(N == 0, "unhandled vmcnt");
}
#define BAR()    asm volatile("s_barrier" ::: "memory")
#define LGKM0()  do { asm volatile("s_waitcnt lgkmcnt(0)" ::: "memory"); \
                      __builtin_amdgcn_sched_barrier(0); } while (0)

__device__ __forceinline__ float gelu_f(float v) {
  float u = v * (0.7978845608f + 0.0356774081f * v * v);
  float t = 1.f - 2.f / (1.f + __expf(2.f * u));   // tanh(u), correct +/-inf limits
  return 0.5f * v * (1.f + t);
}

// ---------------- router: fp32 logits, softmax, top-2, renorm (NO atomics) ----------------
__global__ __launch_bounds__(256) void k_router(const float* __restrict__ x,
    const float* __restrict__ wr, int* __restrict__ tki, float* __restrict__ tkw) {
  int wid = threadIdx.x >> 6, lane = threadIdx.x & 63;
  int t = blockIdx.x * 4 + wid;
  const float* xp = x + (size_t)t * D_;
  float pa[E_];
#pragma unroll
  for (int e = 0; e < E_; ++e) pa[e] = 0.f;
#pragma unroll
  for (int it = 0; it < D_ / 64; ++it) {
    int d = it * 64 + lane;
    float xv = xp[d];
    const float4* wp = (const float4*)(wr + (size_t)d * E_);
    float4 a = wp[0], b = wp[1];
    pa[0] += xv * a.x; pa[1] += xv * a.y; pa[2] += xv * a.z; pa[3] += xv * a.w;
    pa[4] += xv * b.x; pa[5] += xv * b.y; pa[6] += xv * b.z; pa[7] += xv * b.w;
  }
#pragma unroll
  for (int e = 0; e < E_; ++e) {
    float v = pa[e];
    for (int off = 32; off; off >>= 1) v += __shfl_xor(v, off);
    pa[e] = v;
  }
  if (lane == 0) {
    float m = pa[0];
#pragma unroll
    for (int e = 1; e < E_; ++e) m = fmaxf(m, pa[e]);
    float p[E_], s = 0.f;
#pragma unroll
    for (int e = 0; e < E_; ++e) { p[e] = expf(pa[e] - m); s += p[e]; }
#pragma unroll
    for (int e = 0; e < E_; ++e) p[e] = p[e] / s;
    int i0 = 0; float b0 = p[0];
#pragma unroll
    for (int e = 1; e < E_; ++e) if (p[e] > b0) { b0 = p[e]; i0 = e; }
    int i1 = -1; float b1v = -1.f;
#pragma unroll
    for (int e = 0; e < E_; ++e) if (e != i0 && p[e] > b1v) { b1v = p[e]; i1 = e; }
    float den = b0 + b1v + 1e-8f;
    tki[t * 2] = i0; tki[t * 2 + 1] = i1;
    tkw[t * 2] = b0 / den; tkw[t * 2 + 1] = b1v / den;
  }
}

// ---- single-block routing: histogram -> scan -> 256-aligned offsets -> ordered slots ----
__global__ __launch_bounds__(256) void k_route_all(const int* __restrict__ tki,
    int* __restrict__ stok, int* __restrict__ tslot, int* __restrict__ aoff) {
  __shared__ int cl[256][E_];
  __shared__ int tot[E_];
  __shared__ int aoffA[E_ + 1];
  int tid = threadIdx.x;
  for (int i = tid; i < NSLOTP; i += 256) stok[i] = -1;
#pragma unroll
  for (int e = 0; e < E_; ++e) cl[tid][e] = 0;
  int t0 = tid * (NTOK / 256);
#pragma unroll
  for (int i = 0; i < NTOK / 256; ++i) {
    cl[tid][tki[(t0 + i) * 2]]++;
    cl[tid][tki[(t0 + i) * 2 + 1]]++;
  }
  __syncthreads();
  if (tid < E_) {
    int run = 0;
    for (int i = 0; i < 256; ++i) { int v = cl[i][tid]; cl[i][tid] = run; run += v; }
    tot[tid] = run;
  }
  __syncthreads();
  if (tid == 0) {
    int a = 0; aoffA[0] = 0; aoff[0] = 0;
    for (int e = 0; e < E_; ++e) { a += ((tot[e] + 255) >> 8) << 8; aoffA[e + 1] = a; aoff[e + 1] = a; }
  }
  __syncthreads();
#pragma unroll
  for (int i = 0; i < NTOK / 256; ++i) {
    int t = t0 + i;
#pragma unroll
    for (int k = 0; k < 2; ++k) {
      int e = tki[t * 2 + k];
      int pos = aoffA[e] + cl[tid][e];
      cl[tid][e]++;
      stok[pos] = t;
      tslot[t * 2 + k] = pos;
    }
  }
}

// -------- gather x rows into bf16 slot matrix (zeros for padding) --------
__global__ __launch_bounds__(256) void k_gather(const float* __restrict__ x,
    const int* __restrict__ stok, __bf16* __restrict__ Xg) {
  int i8 = blockIdx.x * 256 + threadIdx.x;
  int flat = i8 * 8;
  int row = flat / D_;
  int col = flat - row * D_;
  int tok = stok[row];
  bf16x8 v;
  if (tok >= 0) {
    const float4* s = (const float4*)(x + (size_t)tok * D_ + col);
    float4 a = s[0], b = s[1];
    v[0] = (__bf16)a.x; v[1] = (__bf16)a.y; v[2] = (__bf16)a.z; v[3] = (__bf16)a.w;
    v[4] = (__bf16)b.x; v[5] = (__bf16)b.y; v[6] = (__bf16)b.z; v[7] = (__bf16)b.w;
  } else {
#pragma unroll
    for (int k = 0; k < 8; ++k) v[k] = (__bf16)0.f;
  }
  *(bf16x8*)(Xg + (size_t)flat) = v;
}

// -------- fp32 [R][C] -> bf16 [C][R] per expert --------
__global__ __launch_bounds__(256) void k_transpose(const float* __restrict__ in,
    __bf16* __restrict__ outp, int R, int C) {
  __shared__ float Ts[64][65];
  int e = blockIdx.z;
  int r0 = blockIdx.y * 64, c0 = blockIdx.x * 64;
  const float* ip = in + (size_t)e * R * C;
  int lr = threadIdx.x >> 4;
  int lc = (threadIdx.x & 15) * 4;
#pragma unroll
  for (int it = 0; it < 4; ++it) {
    int r = lr + it * 16;
    float4 v = *(const float4*)(ip + (size_t)(r0 + r) * C + c0 + lc);
    Ts[r][lc] = v.x; Ts[r][lc + 1] = v.y; Ts[r][lc + 2] = v.z; Ts[r][lc + 3] = v.w;
  }
  __syncthreads();
  int rr = (threadIdx.x & 7) * 8;
  int cc = threadIdx.x >> 3;
  __bf16* op = outp + (size_t)e * R * C + r0 + rr;
#pragma unroll
  for (int it = 0; it < 2; ++it) {
    int c = cc + it * 32;
    bf16x8 v;
#pragma unroll
    for (int i = 0; i < 8; ++i) v[i] = (__bf16)Ts[rr + i][c];
    *(bf16x8*)(op + (size_t)(c0 + c) * R) = v;
  }
}

// ===== GEMM1: 256x256 tile, BK=64, 8 waves (2Mx4N, per-wave 128x64), 128KB dbuf =====
// Stage-halves == consumption-halves:
//   A-half m: global tile rows {m*64+u} U {128+m*64+u}  -> LDS p = m*128 + q*64 + u
//   B-half n: strips {wc*64+n*32+s}                      -> LDS p = n*128 + wc*32 + s
// Phases per K-tile t: p0 Q(m0,n0)+stage A-m1(t+1); p1 Q(m0,n1)+stage B-n1(t+1);
//   p2 Q(m1,n0)+stage A-m0(t+2); p3 Q(m1,n1)+stage B-n0(t+2); end: vmcnt(4)
//   (retires through B-n1(t+1) => tile t+1 resident; t+2's two stages stay in flight).
// H = gelu(Xg @ w1t^T + b1)
__global__ __launch_bounds__(512, 2) void k_gemm1(
    const __bf16* __restrict__ Ag, const __bf16* __restrict__ Bt,
    const float* __restrict__ bias, const int* __restrict__ aoff,
    __bf16* __restrict__ Hout) {
  constexpr int KST = D_, N = F_, NK = KST / 64;                  // 12 K-tiles
  constexpr int BUFE = 256 * 64;                                  // elems per buf
  constexpr int NB = N / 256, NMB = NSLOTP / 256, NWG = NB * NMB; // 12*40=480

  __shared__ __align__(16) __bf16 Als[2 * BUFE];   // 64KB
  __shared__ __align__(16) __bf16 Bls[2 * BUFE];   // 64KB

  int bswz = (blockIdx.x & 7) * (NWG / 8) + (blockIdx.x >> 3);   // XCD-bijective
  int mb = bswz % NMB, nb = bswz / NMB;                          // mb-fast: B panel hot
  int row0 = mb * 256;
  if (row0 >= aoff[E_]) return;
  int e = 0;
#pragma unroll
  for (int q = 0; q < E_; ++q) if (row0 >= aoff[q + 1]) e = q + 1;
  const __bf16* Bp = Bt + (size_t)e * D_ * F_;

  int tid = threadIdx.x, w = tid >> 6, l = tid & 63;
  int fr = l & 15, fg = l >> 4;
  int wr = w >> 2, wc = w & 3;            // wave tile: rows wr*128, cols wc*64
  int ur = tid >> 3, us = tid & 7;        // staging: row-in-64-unit / 16B slot
  int src_sl = us ^ (ur & 7);             // pre-swizzled global chunk (involution)
  int r7 = fr & 7;

  auto SH_A = [&](int kt, int b, int m) {
#pragma unroll
    for (int q = 0; q < 2; ++q) {
      int grow = q * 128 + m * 64 + ur;
      gload_lds16(Ag + (size_t)(row0 + grow) * KST + kt * 64 + src_sl * 8,
                  Als + b * BUFE + (m * 128 + q * 64) * 64 + tid * 8);
    }
  };
  auto SH_B = [&](int kt, int b, int n) {
#pragma unroll
    for (int q = 0; q < 2; ++q) {
      int grow = ((q << 1) + (ur >> 5)) * 64 + n * 32 + (ur & 31);
      gload_lds16(Bp + (size_t)(nb * 256 + grow) * KST + kt * 64 + src_sl * 8,
                  Bls + b * BUFE + (n * 128 + q * 64) * 64 + tid * 8);
    }
  };

  // prologue: tile0 fully + tile1's {A-m0, B-n0}; leave the latter (4 instrs) in flight
  SH_A(0, 0, 0); SH_B(0, 0, 0); SH_A(0, 0, 1); SH_B(0, 0, 1);
  SH_A(1, 1, 0); SH_B(1, 1, 0);
  wait_vmcnt<4>();
  __builtin_amdgcn_sched_barrier(0);
  BAR();

  f32x4 acc[8][4] = {};
  bf16x8 af[4][2], bfr[2][2][2];          // bfr[n][j][kk]
  for (int kt = 0; kt < NK; ++kt) {
    int b = kt & 1;
    const __bf16* Ab = Als + b * BUFE;
    const __bf16* Bb = Bls + b * BUFE;
    bool s1 = (kt + 1) < NK, s2 = (kt + 2) < NK;
    int b1 = (kt + 1) & 1, b2 = kt & 1;
    // ---- phase 0: Q(m0,n0); read af(m0)+bfr(n0); stage A-m1(t+1) ----
    if (s1) SH_A(kt + 1, b1, 1);
#pragma unroll
    for (int i = 0; i < 4; ++i) {
      int p = wr * 64 + i * 16 + fr;               // m=0: p in [0,128)
#pragma unroll
      for (int kk = 0; kk < 2; ++kk)
        af[i][kk] = *(const bf16x8*)(Ab + p * 64 + (((kk * 4 + fg) ^ r7) << 3));
    }
#pragma unroll
    for (int j = 0; j < 2; ++j) {
      int p = wc * 32 + j * 16 + fr;               // n=0
#pragma unroll
      for (int kk = 0; kk < 2; ++kk)
        bfr[0][j][kk] = *(const bf16x8*)(Bb + p * 64 + (((kk * 4 + fg) ^ r7) << 3));
    }
    LGKM0();
    __builtin_amdgcn_s_setprio(1);
#pragma unroll
    for (int i = 0; i < 4; ++i)
#pragma unroll
      for (int j = 0; j < 2; ++j)
#pragma unroll
        for (int kk = 0; kk < 2; ++kk)
          acc[i][j] = __builtin_amdgcn_mfma_f32_16x16x32_bf16(af[i][kk], bfr[0][j][kk], acc[i][j], 0, 0, 0);
    __builtin_amdgcn_s_setprio(0);
    __builtin_amdgcn_sched_barrier(0);
    BAR();
    // ---- phase 1: Q(m0,n1); read bfr(n1); stage B-n1(t+1) ----
    if (s1) SH_B(kt + 1, b1, 1);
#pragma unroll
    for (int j = 0; j < 2; ++j) {
      int p = 128 + wc * 32 + j * 16 + fr;         // n=1
#pragma unroll
      for (int kk = 0; kk < 2; ++kk)
        bfr[1][j][kk] = *(const bf16x8*)(Bb + p * 64 + (((kk * 4 + fg) ^ r7) << 3));
    }
    LGKM0();
    __builtin_amdgcn_s_setprio(1);
#pragma unroll
    for (int i = 0; i < 4; ++i)
#pragma unroll
      for (int j = 0; j < 2; ++j)
#pragma unroll
        for (int kk = 0; kk < 2; ++kk)
          acc[i][2 + j] = __builtin_amdgcn_mfma_f32_16x16x32_bf16(af[i][kk], bfr[1][j][kk], acc[i][2 + j], 0, 0, 0);
    __builtin_amdgcn_s_setprio(0);
    __builtin_amdgcn_sched_barrier(0);
    BAR();
    // ---- phase 2: Q(m1,n0); read af(m1); stage A-m0(t+2) ----
    if (s2) SH_A(kt + 2, b2, 0);
#pragma unroll
    for (int i = 0; i < 4; ++i) {
      int p = 128 + wr * 64 + i * 16 + fr;         // m=1
#pragma unroll
      for (int kk = 0; kk < 2; ++kk)
        af[i][kk] = *(const bf16x8*)(Ab + p * 64 + (((kk * 4 + fg) ^ r7) << 3));
    }
    LGKM0();
    __builtin_amdgcn_s_setprio(1);
#pragma unroll
    for (int i = 0; i < 4; ++i)
#pragma unroll
      for (int j = 0; j < 2; ++j)
#pragma unroll
        for (int kk = 0; kk < 2; ++kk)
          acc[4 + i][j] = __builtin_amdgcn_mfma_f32_16x16x32_bf16(af[i][kk], bfr[0][j][kk], acc[4 + i][j], 0, 0, 0);
    __builtin_amdgcn_s_setprio(0);
    __builtin_amdgcn_sched_barrier(0);
    BAR();
    // ---- phase 3: Q(m1,n1); stage B-n0(t+2); end: counted retire of tile t+1 ----
    if (s2) SH_B(kt + 2, b2, 0);
    __builtin_amdgcn_s_setprio(1);
#pragma unroll
    for (int i = 0; i < 4; ++i)
#pragma unroll
      for (int j = 0; j < 2; ++j)
#pragma unroll
        for (int kk = 0; kk < 2; ++kk)
          acc[4 + i][2 + j] = __builtin_amdgcn_mfma_f32_16x16x32_bf16(af[i][kk], bfr[1][j][kk], acc[4 + i][2 + j], 0, 0, 0);
    __builtin_amdgcn_s_setprio(0);
    __builtin_amdgcn_sched_barrier(0);
    if (s2)      wait_vmcnt<4>();    // leaves A-m0(t+2),B-n0(t+2) in flight
    else if (s1) wait_vmcnt<0>();    // only t+1's last halves outstanding (issued 2-3 phases ago)
    BAR();
  }

#pragma unroll
  for (int NN = 0; NN < 4; ++NN) {
    int col = nb * 256 + wc * 64 + NN * 16 + fr;
    float bv = bias[e * N + col];
#pragma unroll
    for (int M = 0; M < 8; ++M) {
#pragma unroll
      for (int r = 0; r < 4; ++r) {
        int row = row0 + wr * 128 + M * 16 + fg * 4 + r;
        Hout[(size_t)row * N + col] = (__bf16)gelu_f(acc[M][NN][r] + bv);
      }
    }
  }
}

// ===== GEMM2 (round-5 proven): 2-phase dbuf, BM=128, BN=256, BK=32, split-K=2 =====
// E[kh] = H[:,khalf] @ w2t[:,khalf]^T (+b2 if kh==0), fp16 partials.
template<int KST, int N, int KSPLIT>
__global__ __launch_bounds__(512, 4) void k_gemm2(
    const __bf16* __restrict__ A, const __bf16* __restrict__ Bt,
    const float* __restrict__ bias, const int* __restrict__ aoff,
    f16* __restrict__ E0, f16* __restrict__ E1) {
  constexpr int BN = 256;
  constexpr int ASZ = 128 * 32;
  constexpr int BSZ = BN * 32;
  constexpr int NK = KST / 32 / KSPLIT;
  constexpr int NB = N / BN;
  constexpr int NMB = NSLOTP / 128;
  constexpr int NWGB = NB * NMB;
  constexpr int NWG = NWGB * KSPLIT;

  __shared__ __align__(16) __bf16 Als[2 * ASZ];
  __shared__ __align__(16) __bf16 Bls[2 * BSZ];

  int bswz = (blockIdx.x & 7) * (NWG / 8) + (blockIdx.x >> 3);
  int kh = bswz / NWGB;
  int rem = bswz % NWGB;
  int mb = rem % NMB, nb = rem / NMB;
  int row0 = mb * 128;
  if (row0 >= aoff[E_]) return;
  int e = 0;
#pragma unroll
  for (int q = 0; q < E_; ++q) if (row0 >= aoff[q + 1]) e = q + 1;
  const __bf16* Bp = Bt + (size_t)e * D_ * F_;
  int kbase = kh * (KST / KSPLIT);

  int tid = threadIdx.x, w = tid >> 6, l = tid & 63;
  int lr = l >> 2, ls = l & 3;
  int fr = l & 15, fg = l >> 4;
  int wrow = (w >> 2) * 64, wcol = (w & 3) * 64;

  auto STAGE = [&](int kt, int b) {
    int k0 = kbase + kt * 32;
    {
      int rowA = w * 16 + lr;
      int sA = ls ^ ((rowA >> 1) & 3);
      gload_lds16(A + (size_t)(row0 + rowA) * KST + k0 + sA * 8, Als + b * ASZ + w * 512);
    }
#pragma unroll
    for (int q = 0; q < 2; ++q) {
      int idx = w * 2 + q;
      int rowB = idx * 16 + lr;
      int sB = ls ^ ((rowB >> 1) & 3);
      gload_lds16(Bp + (size_t)(nb * BN + rowB) * KST + k0 + sB * 8, Bls + b * BSZ + idx * 512);
    }
  };

  f32x4 acc[4][4] = {};
  STAGE(0, 0);
  asm volatile("s_waitcnt vmcnt(0)" ::: "memory");
  __builtin_amdgcn_sched_barrier(0);
  __builtin_amdgcn_s_barrier();
  for (int t = 0; t < NK; ++t) {
    int cur = t & 1;
    if (t + 1 < NK) STAGE(t + 1, cur ^ 1);
    __builtin_amdgcn_sched_barrier(0);
    bf16x8 af[4], bfr[4];
#pragma unroll
    for (int i = 0; i < 4; ++i) {
      int rl = wrow + i * 16 + fr;
      af[i] = *(const bf16x8*)(Als + cur * ASZ + rl * 32 + ((fg ^ ((rl >> 1) & 3)) << 3));
    }
#pragma unroll
    for (int j = 0; j < 4; ++j) {
      int nl = wcol + j * 16 + fr;
      bfr[j] = *(const bf16x8*)(Bls + cur * BSZ + nl * 32 + ((fg ^ ((nl >> 1) & 3)) << 3));
    }
#pragma unroll
    for (int i = 0; i < 4; ++i)
#pragma unroll
      for (int j = 0; j < 4; ++j)
        acc[i][j] = __builtin_amdgcn_mfma_f32_16x16x32_bf16(af[i], bfr[j], acc[i][j], 0, 0, 0);
    __builtin_amdgcn_sched_barrier(0);
    asm volatile("s_waitcnt vmcnt(0)" ::: "memory");
    __builtin_amdgcn_s_barrier();
  }

  f16* Ep = (kh == 0) ? E0 : E1;
#pragma unroll
  for (int j = 0; j < 4; ++j) {
    int col = nb * BN + wcol + j * 16 + fr;
    float bv = (kh == 0) ? bias[e * N + col] : 0.f;
#pragma unroll
    for (int i = 0; i < 4; ++i) {
#pragma unroll
      for (int r = 0; r < 4; ++r) {
        int row = row0 + wrow + i * 16 + fg * 4 + r;
        Ep[(size_t)row * N + col] = (f16)(acc[i][j][r] + bv);
      }
    }
  }
}

// -------- combine: out[t] = w0*(E0+E1)[s0] + w1*(E0+E1)[s1]  (fp16 partials) --------
__global__ __launch_bounds__(256) void k_combine(const f16* __restrict__ E0,
    const f16* __restrict__ E1, const int* __restrict__ tslot,
    const float* __restrict__ tkw, float* __restrict__ out) {
  int idx = blockIdx.x * 256 + threadIdx.x;        // per 8 elems
  int t = idx / (D_ / 8);
  int c8 = (idx - t * (D_ / 8)) * 8;
  int s0 = tslot[2 * t], s1 = tslot[2 * t + 1];
  float w0 = tkw[2 * t], w1 = tkw[2 * t + 1];
  f16x8 a0 = *(const f16x8*)(E0 + (size_t)s0 * D_ + c8);
  f16x8 b0 = *(const f16x8*)(E0 + (size_t)s1 * D_ + c8);
  f16x8 a1 = *(const f16x8*)(E1 + (size_t)s0 * D_ + c8);
  f16x8 b1 = *(const f16x8*)(E1 + (size_t)s1 * D_ + c8);
  float o[8];
#pragma unroll
  for (int k = 0; k < 8; ++k)
    o[k] = w0 * ((float)a0[k] + (float)a1[k]) + w1 * ((float)b0[k] + (float)b1[k]);
  *(float4*)(out + (size_t)t * D_ + c8)     = *(float4*)&o[0];
  *(float4*)(out + (size_t)t * D_ + c8 + 4) = *(float4*)&o[4];
}

extern "C" void kernel_launch(void* const* d_in, const int* in_sizes, int n_in,
                              void* d_out, int out_size, void* d_ws, size_t ws_size,
                              hipStream_t stream) {
  const float* x  = (const float*)d_in[0];
  const float* wr = (const float*)d_in[1];
  const float* w1 = (const float*)d_in[2];
  const float* b1 = (const float*)d_in[3];
  const float* w2 = (const float*)d_in[4];
  const float* b2 = (const float*)d_in[5];
  float* out = (float*)d_out;

  char* ws = (char*)d_ws;
  size_t o = 0;
  __bf16* wt  = (__bf16*)(ws + o); o += (size_t)E_ * D_ * F_ * 2;  // w1t, then w2t after GEMM1
  __bf16* Xg  = (__bf16*)(ws + o); o += (size_t)NSLOTP * D_ * 2;   // dead after GEMM1
  __bf16* H   = (__bf16*)(ws + o); o += (size_t)NSLOTP * F_ * 2;
  f16*   E1p  = (f16*)(ws + o);   o += (size_t)NSLOTP * D_ * 2;
  int*   tki  = (int*)(ws + o);   o += (size_t)NTOK * 2 * 4;
  float* tkw  = (float*)(ws + o); o += (size_t)NTOK * 2 * 4;
  int*   stok = (int*)(ws + o);   o += (size_t)NSLOTP * 4;
  int*   tslot= (int*)(ws + o);   o += (size_t)NTOK * 2 * 4;
  int*   aoff = (int*)(ws + o);   o += 64;
  f16*   E0p  = (f16*)Xg;         // alias: Xg dead after GEMM1, identical size
  if (ws_size < o) return;        // ~132.3 MB (= round-7's proven allocation)

  k_router<<<NTOK / 4, 256, 0, stream>>>(x, wr, tki, tkw);
  k_route_all<<<1, 256, 0, stream>>>(tki, stok, tslot, aoff);
  k_gather<<<(NSLOTP * D_ / 8) / 256, 256, 0, stream>>>(x, stok, Xg);
  k_transpose<<<dim3(F_ / 64, D_ / 64, E_), 256, 0, stream>>>(w1, wt, D_, F_);
  // GEMM1: 256x256 fine-phase, 12*40 = 480 blocks
  k_gemm1<<<(F_ / 256) * (NSLOTP / 256), 512, 0, stream>>>(Xg, wt, b1, aoff, H);
  // transpose w2 into the (now dead) wt slot
  k_transpose<<<dim3(D_ / 64, F_ / 64, E_), 256, 0, stream>>>(w2, wt, F_, D_);
  // GEMM2: K=3072, N=768, split-K=2 -> 2*3*80 = 480 blocks
  k_gemm2<F_, D_, 2><<<2 * (D_ / 256) * (NSLOTP / 128), 512, 0, stream>>>(
      H, wt, b2, aoff, E0p, E1p);
  k_combine<<<NTOK * (D_ / 8) / 256, 256, 0, stream>>>(E0p, E1p, tslot, tkw, out);
}

// Round 10
// 202.055 us; speedup vs baseline: 1.2413x; 1.0599x over previous
//
#include <hip/hip_runtime.h>
#include <math.h>

typedef __bf16 bf16x8 __attribute__((ext_vector_type(8)));
typedef float f32x4 __attribute__((ext_vector_type(4)));
typedef _Float16 f16;
typedef _Float16 f16x8 __attribute__((ext_vector_type(8)));

#define B_ 4
#define S_ 1024
#define D_ 768
#define F_ 3072
#define E_ 8
#define NTOK 4096
#define NSLOTP 9216   // 8192 slots + per-expert pad to 128

__device__ __forceinline__ void gload_lds16(const void* g, void* s) {
  __builtin_amdgcn_global_load_lds((const __attribute__((address_space(1))) void*)g,
                                   (__attribute__((address_space(3))) void*)s, 16, 0, 0);
}

__device__ __forceinline__ float gelu_f(float v) {
  float u = v * (0.7978845608f + 0.0356774081f * v * v);
  float t = 1.f - 2.f / (1.f + __expf(2.f * u));   // tanh(u), correct +/-inf limits
  return 0.5f * v * (1.f + t);
}

// ---------------- router: fp32 logits, softmax, top-2, renorm (NO atomics) ----------------
__global__ __launch_bounds__(256) void k_router(const float* __restrict__ x,
    const float* __restrict__ wr, int* __restrict__ tki, float* __restrict__ tkw) {
  int wid = threadIdx.x >> 6, lane = threadIdx.x & 63;
  int t = blockIdx.x * 4 + wid;
  const float* xp = x + (size_t)t * D_;
  float pa[E_];
#pragma unroll
  for (int e = 0; e < E_; ++e) pa[e] = 0.f;
#pragma unroll
  for (int it = 0; it < D_ / 64; ++it) {
    int d = it * 64 + lane;
    float xv = xp[d];
    const float4* wp = (const float4*)(wr + (size_t)d * E_);
    float4 a = wp[0], b = wp[1];
    pa[0] += xv * a.x; pa[1] += xv * a.y; pa[2] += xv * a.z; pa[3] += xv * a.w;
    pa[4] += xv * b.x; pa[5] += xv * b.y; pa[6] += xv * b.z; pa[7] += xv * b.w;
  }
#pragma unroll
  for (int e = 0; e < E_; ++e) {
    float v = pa[e];
    for (int off = 32; off; off >>= 1) v += __shfl_xor(v, off);
    pa[e] = v;
  }
  if (lane == 0) {
    float m = pa[0];
#pragma unroll
    for (int e = 1; e < E_; ++e) m = fmaxf(m, pa[e]);
    float p[E_], s = 0.f;
#pragma unroll
    for (int e = 0; e < E_; ++e) { p[e] = expf(pa[e] - m); s += p[e]; }
#pragma unroll
    for (int e = 0; e < E_; ++e) p[e] = p[e] / s;
    int i0 = 0; float b0 = p[0];
#pragma unroll
    for (int e = 1; e < E_; ++e) if (p[e] > b0) { b0 = p[e]; i0 = e; }
    int i1 = -1; float b1v = -1.f;
#pragma unroll
    for (int e = 0; e < E_; ++e) if (e != i0 && p[e] > b1v) { b1v = p[e]; i1 = e; }
    float den = b0 + b1v + 1e-8f;
    tki[t * 2] = i0; tki[t * 2 + 1] = i1;
    tkw[t * 2] = b0 / den; tkw[t * 2 + 1] = b1v / den;
  }
}

// ---- single-block routing: histogram -> scan -> 128-aligned offsets -> ordered slots ----
__global__ __launch_bounds__(256) void k_route_all(const int* __restrict__ tki,
    int* __restrict__ stok, int* __restrict__ tslot, int* __restrict__ aoff) {
  __shared__ int cl[256][E_];
  __shared__ int tot[E_];
  __shared__ int aoffA[E_ + 1];
  int tid = threadIdx.x;
  for (int i = tid; i < NSLOTP; i += 256) stok[i] = -1;
#pragma unroll
  for (int e = 0; e < E_; ++e) cl[tid][e] = 0;
  int t0 = tid * (NTOK / 256);
#pragma unroll
  for (int i = 0; i < NTOK / 256; ++i) {
    cl[tid][tki[(t0 + i) * 2]]++;
    cl[tid][tki[(t0 + i) * 2 + 1]]++;
  }
  __syncthreads();
  if (tid < E_) {
    int run = 0;
    for (int i = 0; i < 256; ++i) { int v = cl[i][tid]; cl[i][tid] = run; run += v; }
    tot[tid] = run;
  }
  __syncthreads();
  if (tid == 0) {
    int a = 0; aoffA[0] = 0; aoff[0] = 0;
    for (int e = 0; e < E_; ++e) { a += ((tot[e] + 127) >> 7) << 7; aoffA[e + 1] = a; aoff[e + 1] = a; }
  }
  __syncthreads();
#pragma unroll
  for (int i = 0; i < NTOK / 256; ++i) {
    int t = t0 + i;
#pragma unroll
    for (int k = 0; k < 2; ++k) {
      int e = tki[t * 2 + k];
      int pos = aoffA[e] + cl[tid][e];
      cl[tid][e]++;
      stok[pos] = t;
      tslot[t * 2 + k] = pos;
    }
  }
}

// -------- gather x rows into bf16 slot matrix (zeros for padding) --------
__global__ __launch_bounds__(256) void k_gather(const float* __restrict__ x,
    const int* __restrict__ stok, __bf16* __restrict__ Xg) {
  int i8 = blockIdx.x * 256 + threadIdx.x;
  int flat = i8 * 8;
  int row = flat / D_;
  int col = flat - row * D_;
  int tok = stok[row];
  bf16x8 v;
  if (tok >= 0) {
    const float4* s = (const float4*)(x + (size_t)tok * D_ + col);
    float4 a = s[0], b = s[1];
    v[0] = (__bf16)a.x; v[1] = (__bf16)a.y; v[2] = (__bf16)a.z; v[3] = (__bf16)a.w;
    v[4] = (__bf16)b.x; v[5] = (__bf16)b.y; v[6] = (__bf16)b.z; v[7] = (__bf16)b.w;
  } else {
#pragma unroll
    for (int k = 0; k < 8; ++k) v[k] = (__bf16)0.f;
  }
  *(bf16x8*)(Xg + (size_t)flat) = v;
}

// -------- fp32 [R][C] -> bf16 [C][R] per expert --------
__global__ __launch_bounds__(256) void k_transpose(const float* __restrict__ in,
    __bf16* __restrict__ outp, int R, int C) {
  __shared__ float Ts[64][65];
  int e = blockIdx.z;
  int r0 = blockIdx.y * 64, c0 = blockIdx.x * 64;
  const float* ip = in + (size_t)e * R * C;
  int lr = threadIdx.x >> 4;
  int lc = (threadIdx.x & 15) * 4;
#pragma unroll
  for (int it = 0; it < 4; ++it) {
    int r = lr + it * 16;
    float4 v = *(const float4*)(ip + (size_t)(r0 + r) * C + c0 + lc);
    Ts[r][lc] = v.x; Ts[r][lc + 1] = v.y; Ts[r][lc + 2] = v.z; Ts[r][lc + 3] = v.w;
  }
  __syncthreads();
  int rr = (threadIdx.x & 7) * 8;
  int cc = threadIdx.x >> 3;
  __bf16* op = outp + (size_t)e * R * C + r0 + rr;
#pragma unroll
  for (int it = 0; it < 2; ++it) {
    int c = cc + it * 32;
    bf16x8 v;
#pragma unroll
    for (int i = 0; i < 8; ++i) v[i] = (__bf16)Ts[rr + i][c];
    *(bf16x8*)(op + (size_t)(c0 + c) * R) = v;
  }
}

// ===== GEMM1 (round-5 proven, 79.8us): 2-phase dbuf, BM=128, BN=256, BK=32, =====
// ===== 8 waves (2x4, per-wave 64x64), 48KB LDS, 4 blocks/CU.               =====
// H = gelu(Xg @ w1t^T + b1)
__global__ __launch_bounds__(512, 4) void k_gemm1(
    const __bf16* __restrict__ A, const __bf16* __restrict__ Bt,
    const float* __restrict__ bias, const int* __restrict__ aoff,
    __bf16* __restrict__ Hout) {
  constexpr int KST = D_, N = F_;
  constexpr int BN = 256;
  constexpr int ASZ = 128 * 32;
  constexpr int BSZ = BN * 32;
  constexpr int NK = KST / 32;
  constexpr int NB = N / BN;
  constexpr int NMB = NSLOTP / 128;
  constexpr int NWG = NB * NMB;                    // 12*72 = 864

  __shared__ __align__(16) __bf16 Als[2 * ASZ];
  __shared__ __align__(16) __bf16 Bls[2 * BSZ];

  int bswz = (blockIdx.x & 7) * (NWG / 8) + (blockIdx.x >> 3);   // bijective, NWG%8==0
  int mb = bswz % NMB, nb = bswz / NMB;                          // mb-fast: B panel L2-hot
  int row0 = mb * 128;
  if (row0 >= aoff[E_]) return;
  int e = 0;
#pragma unroll
  for (int q = 0; q < E_; ++q) if (row0 >= aoff[q + 1]) e = q + 1;
  const __bf16* Bp = Bt + (size_t)e * D_ * F_;

  int tid = threadIdx.x, w = tid >> 6, l = tid & 63;
  int lr = l >> 2, ls = l & 3;      // staging lane -> row-in-16 / 16B slot
  int fr = l & 15, fg = l >> 4;     // fragment lane -> row / k-group
  int wrow = (w >> 2) * 64, wcol = (w & 3) * 64;

  auto STAGE = [&](int kt, int b) {
    int k0 = kt * 32;
    {
      int rowA = w * 16 + lr;
      int sA = ls ^ ((rowA >> 1) & 3);
      gload_lds16(A + (size_t)(row0 + rowA) * KST + k0 + sA * 8, Als + b * ASZ + w * 512);
    }
#pragma unroll
    for (int q = 0; q < 2; ++q) {
      int idx = w * 2 + q;
      int rowB = idx * 16 + lr;
      int sB = ls ^ ((rowB >> 1) & 3);
      gload_lds16(Bp + (size_t)(nb * BN + rowB) * KST + k0 + sB * 8, Bls + b * BSZ + idx * 512);
    }
  };

  f32x4 acc[4][4] = {};
  STAGE(0, 0);
  asm volatile("s_waitcnt vmcnt(0)" ::: "memory");
  __builtin_amdgcn_sched_barrier(0);
  __builtin_amdgcn_s_barrier();
  for (int t = 0; t < NK; ++t) {
    int cur = t & 1;
    if (t + 1 < NK) STAGE(t + 1, cur ^ 1);         // issue next-tile loads FIRST
    __builtin_amdgcn_sched_barrier(0);
    bf16x8 af[4], bfr[4];
#pragma unroll
    for (int i = 0; i < 4; ++i) {
      int rl = wrow + i * 16 + fr;
      af[i] = *(const bf16x8*)(Als + cur * ASZ + rl * 32 + ((fg ^ ((rl >> 1) & 3)) << 3));
    }
#pragma unroll
    for (int j = 0; j < 4; ++j) {
      int nl = wcol + j * 16 + fr;
      bfr[j] = *(const bf16x8*)(Bls + cur * BSZ + nl * 32 + ((fg ^ ((nl >> 1) & 3)) << 3));
    }
#pragma unroll
    for (int i = 0; i < 4; ++i)
#pragma unroll
      for (int j = 0; j < 4; ++j)
        acc[i][j] = __builtin_amdgcn_mfma_f32_16x16x32_bf16(af[i], bfr[j], acc[i][j], 0, 0, 0);
    __builtin_amdgcn_sched_barrier(0);
    asm volatile("s_waitcnt vmcnt(0)" ::: "memory");  // hidden under MFMA
    __builtin_amdgcn_s_barrier();
  }

#pragma unroll
  for (int j = 0; j < 4; ++j) {
    int col = nb * BN + wcol + j * 16 + fr;
    float bv = bias[e * N + col];
#pragma unroll
    for (int i = 0; i < 4; ++i) {
#pragma unroll
      for (int r = 0; r < 4; ++r) {
        int row = row0 + wrow + i * 16 + fg * 4 + r;
        Hout[(size_t)row * N + col] = (__bf16)gelu_f(acc[i][j][r] + bv);
      }
    }
  }
}

// ===== GEMM2 (round-9 proven): 2-phase dbuf, BM=128, BN=256, BK=32, split-K=2 =====
// E[kh] = H[:,khalf] @ w2t[:,khalf]^T (+b2 if kh==0), fp16 partials.
__global__ __launch_bounds__(512, 4) void k_gemm2(
    const __bf16* __restrict__ A, const __bf16* __restrict__ Bt,
    const float* __restrict__ bias, const int* __restrict__ aoff,
    f16* __restrict__ E0, f16* __restrict__ E1) {
  constexpr int KST = F_, N = D_;
  constexpr int BN = 256;
  constexpr int ASZ = 128 * 32;
  constexpr int BSZ = BN * 32;
  constexpr int NK = KST / 32 / 2;
  constexpr int NB = N / BN;
  constexpr int NMB = NSLOTP / 128;
  constexpr int NWGB = NB * NMB;                   // 3*72 = 216
  constexpr int NWG = NWGB * 2;                    // 432

  __shared__ __align__(16) __bf16 Als[2 * ASZ];
  __shared__ __align__(16) __bf16 Bls[2 * BSZ];

  int bswz = (blockIdx.x & 7) * (NWG / 8) + (blockIdx.x >> 3);
  int kh = bswz / NWGB;
  int rem = bswz % NWGB;
  int mb = rem % NMB, nb = rem / NMB;
  int row0 = mb * 128;
  if (row0 >= aoff[E_]) return;
  int e = 0;
#pragma unroll
  for (int q = 0; q < E_; ++q) if (row0 >= aoff[q + 1]) e = q + 1;
  const __bf16* Bp = Bt + (size_t)e * D_ * F_;
  int kbase = kh * (KST / 2);

  int tid = threadIdx.x, w = tid >> 6, l = tid & 63;
  int lr = l >> 2, ls = l & 3;
  int fr = l & 15, fg = l >> 4;
  int wrow = (w >> 2) * 64, wcol = (w & 3) * 64;

  auto STAGE = [&](int kt, int b) {
    int k0 = kbase + kt * 32;
    {
      int rowA = w * 16 + lr;
      int sA = ls ^ ((rowA >> 1) & 3);
      gload_lds16(A + (size_t)(row0 + rowA) * KST + k0 + sA * 8, Als + b * ASZ + w * 512);
    }
#pragma unroll
    for (int q = 0; q < 2; ++q) {
      int idx = w * 2 + q;
      int rowB = idx * 16 + lr;
      int sB = ls ^ ((rowB >> 1) & 3);
      gload_lds16(Bp + (size_t)(nb * BN + rowB) * KST + k0 + sB * 8, Bls + b * BSZ + idx * 512);
    }
  };

  f32x4 acc[4][4] = {};
  STAGE(0, 0);
  asm volatile("s_waitcnt vmcnt(0)" ::: "memory");
  __builtin_amdgcn_sched_barrier(0);
  __builtin_amdgcn_s_barrier();
  for (int t = 0; t < NK; ++t) {
    int cur = t & 1;
    if (t + 1 < NK) STAGE(t + 1, cur ^ 1);
    __builtin_amdgcn_sched_barrier(0);
    bf16x8 af[4], bfr[4];
#pragma unroll
    for (int i = 0; i < 4; ++i) {
      int rl = wrow + i * 16 + fr;
      af[i] = *(const bf16x8*)(Als + cur * ASZ + rl * 32 + ((fg ^ ((rl >> 1) & 3)) << 3));
    }
#pragma unroll
    for (int j = 0; j < 4; ++j) {
      int nl = wcol + j * 16 + fr;
      bfr[j] = *(const bf16x8*)(Bls + cur * BSZ + nl * 32 + ((fg ^ ((nl >> 1) & 3)) << 3));
    }
#pragma unroll
    for (int i = 0; i < 4; ++i)
#pragma unroll
      for (int j = 0; j < 4; ++j)
        acc[i][j] = __builtin_amdgcn_mfma_f32_16x16x32_bf16(af[i], bfr[j], acc[i][j], 0, 0, 0);
    __builtin_amdgcn_sched_barrier(0);
    asm volatile("s_waitcnt vmcnt(0)" ::: "memory");
    __builtin_amdgcn_s_barrier();
  }

  f16* Ep = (kh == 0) ? E0 : E1;
#pragma unroll
  for (int j = 0; j < 4; ++j) {
    int col = nb * BN + wcol + j * 16 + fr;
    float bv = (kh == 0) ? bias[e * N + col] : 0.f;
#pragma unroll
    for (int i = 0; i < 4; ++i) {
#pragma unroll
      for (int r = 0; r < 4; ++r) {
        int row = row0 + wrow + i * 16 + fg * 4 + r;
        Ep[(size_t)row * N + col] = (f16)(acc[i][j][r] + bv);
      }
    }
  }
}

// -------- combine: out[t] = w0*(E0+E1)[s0] + w1*(E0+E1)[s1]  (fp16 partials) --------
__global__ __launch_bounds__(256) void k_combine(const f16* __restrict__ E0,
    const f16* __restrict__ E1, const int* __restrict__ tslot,
    const float* __restrict__ tkw, float* __restrict__ out) {
  int idx = blockIdx.x * 256 + threadIdx.x;        // per 8 elems
  int t = idx / (D_ / 8);
  int c8 = (idx - t * (D_ / 8)) * 8;
  int s0 = tslot[2 * t], s1 = tslot[2 * t + 1];
  float w0 = tkw[2 * t], w1 = tkw[2 * t + 1];
  f16x8 a0 = *(const f16x8*)(E0 + (size_t)s0 * D_ + c8);
  f16x8 b0 = *(const f16x8*)(E0 + (size_t)s1 * D_ + c8);
  f16x8 a1 = *(const f16x8*)(E1 + (size_t)s0 * D_ + c8);
  f16x8 b1 = *(const f16x8*)(E1 + (size_t)s1 * D_ + c8);
  float o[8];
#pragma unroll
  for (int k = 0; k < 8; ++k)
    o[k] = w0 * ((float)a0[k] + (float)a1[k]) + w1 * ((float)b0[k] + (float)b1[k]);
  *(float4*)(out + (size_t)t * D_ + c8)     = *(float4*)&o[0];
  *(float4*)(out + (size_t)t * D_ + c8 + 4) = *(float4*)&o[4];
}

extern "C" void kernel_launch(void* const* d_in, const int* in_sizes, int n_in,
                              void* d_out, int out_size, void* d_ws, size_t ws_size,
                              hipStream_t stream) {
  const float* x  = (const float*)d_in[0];
  const float* wr = (const float*)d_in[1];
  const float* w1 = (const float*)d_in[2];
  const float* b1 = (const float*)d_in[3];
  const float* w2 = (const float*)d_in[4];
  const float* b2 = (const float*)d_in[5];
  float* out = (float*)d_out;

  char* ws = (char*)d_ws;
  size_t o = 0;
  __bf16* wt  = (__bf16*)(ws + o); o += (size_t)E_ * D_ * F_ * 2;  // w1t, then w2t after GEMM1
  __bf16* Xg  = (__bf16*)(ws + o); o += (size_t)NSLOTP * D_ * 2;   // dead after GEMM1
  __bf16* H   = (__bf16*)(ws + o); o += (size_t)NSLOTP * F_ * 2;
  f16*   E1p  = (f16*)(ws + o);   o += (size_t)NSLOTP * D_ * 2;
  int*   tki  = (int*)(ws + o);   o += (size_t)NTOK * 2 * 4;
  float* tkw  = (float*)(ws + o); o += (size_t)NTOK * 2 * 4;
  int*   stok = (int*)(ws + o);   o += (size_t)NSLOTP * 4;
  int*   tslot= (int*)(ws + o);   o += (size_t)NTOK * 2 * 4;
  int*   aoff = (int*)(ws + o);   o += 64;
  f16*   E0p  = (f16*)Xg;         // alias: Xg dead after GEMM1, identical size
  if (ws_size < o) return;        // ~123 MB (< proven 147 MB)

  k_router<<<NTOK / 4, 256, 0, stream>>>(x, wr, tki, tkw);
  k_route_all<<<1, 256, 0, stream>>>(tki, stok, tslot, aoff);
  k_gather<<<(NSLOTP * D_ / 8) / 256, 256, 0, stream>>>(x, stok, Xg);
  k_transpose<<<dim3(F_ / 64, D_ / 64, E_), 256, 0, stream>>>(w1, wt, D_, F_);
  // GEMM1: 12*72 = 864 blocks (proven round-5 config)
  k_gemm1<<<(F_ / 256) * (NSLOTP / 128), 512, 0, stream>>>(Xg, wt, b1, aoff, H);
  // transpose w2 into the (now dead) wt slot
  k_transpose<<<dim3(D_ / 64, F_ / 64, E_), 256, 0, stream>>>(w2, wt, F_, D_);
  // GEMM2: split-K=2 -> 432 blocks, fp16 partials
  k_gemm2<<<2 * (D_ / 256) * (NSLOTP / 128), 512, 0, stream>>>(
      H, wt, b2, aoff, E0p, E1p);
  k_combine<<<NTOK * (D_ / 8) / 256, 256, 0, stream>>>(E0p, E1p, tslot, tkw, out);
}